// Round 1
// baseline (784.664 us; speedup 1.0000x reference)
//
#include <hip/hip_runtime.h>
#include <stdint.h>

// Problem constants (from reference setup_inputs)
#define M_TOK 4096
#define K_IN  4096
#define N_OUT 11008
#define GROUPS 64          // K_IN / 64
#define WPR 512            // packed words per weight row = K_IN/8

#define BM 128
#define BN 128
#define BK 64

typedef __bf16 bf16x8 __attribute__((ext_vector_type(8)));
typedef float  f32x4  __attribute__((ext_vector_type(4)));

__device__ __forceinline__ uint16_t f2bf(float f) {
  // round-to-nearest-even fp32 -> bf16 (bit trick; inputs are finite)
  uint32_t u = __float_as_uint(f);
  u += 0x7FFFu + ((u >> 16) & 1u);
  return (uint16_t)(u >> 16);
}

// ---------------------------------------------------------------------------
// Kernel 1: x fp32 -> bf16 (8 elems/thread)
// ---------------------------------------------------------------------------
__global__ __launch_bounds__(256) void convert_x(const float* __restrict__ x,
                                                 uint16_t* __restrict__ xb) {
  size_t i = ((size_t)blockIdx.x * 256 + threadIdx.x) * 8;
  const float4* p = (const float4*)(x + i);
  float4 a = p[0];
  float4 b = p[1];
  uint32_t w0 = (uint32_t)f2bf(a.x) | ((uint32_t)f2bf(a.y) << 16);
  uint32_t w1 = (uint32_t)f2bf(a.z) | ((uint32_t)f2bf(a.w) << 16);
  uint32_t w2 = (uint32_t)f2bf(b.x) | ((uint32_t)f2bf(b.y) << 16);
  uint32_t w3 = (uint32_t)f2bf(b.z) | ((uint32_t)f2bf(b.w) << 16);
  uint4 v; v.x = w0; v.y = w1; v.z = w2; v.w = w3;
  *(uint4*)(xb + i) = v;
}

// ---------------------------------------------------------------------------
// Kernel 2: dequantize int4 W -> bf16 (N x K row-major). 1 thread / int32 word.
// w[o, p*8+j] = scales[o,g] * (nibble - zp[o,g]),  g = p/8
// ---------------------------------------------------------------------------
__global__ __launch_bounds__(256) void dequant_w(const uint32_t* __restrict__ qw,
                                                 const uint32_t* __restrict__ qz,
                                                 const float* __restrict__ sc,
                                                 uint16_t* __restrict__ wb) {
  int idx = blockIdx.x * 256 + threadIdx.x;   // word index < N_OUT*WPR
  int o = idx >> 9;        // / WPR
  int p = idx & 511;
  int g = p >> 3;
  uint32_t zw = qz[o * (GROUPS / 8) + (g >> 3)];
  float zp = (float)((zw >> ((g & 7) * 4)) & 15u);
  float s = sc[o * GROUPS + g];
  float c = -s * zp;
  uint32_t w = qw[idx];
  uint32_t r[4];
#pragma unroll
  for (int j = 0; j < 4; j++) {
    float f0 = (float)((w >> (8 * j)) & 15u);
    float f1 = (float)((w >> (8 * j + 4)) & 15u);
    uint32_t lo = f2bf(fmaf(f0, s, c));
    uint32_t hi = f2bf(fmaf(f1, s, c));
    r[j] = lo | (hi << 16);
  }
  uint4 v; v.x = r[0]; v.y = r[1]; v.z = r[2]; v.w = r[3];
  *(uint4*)(wb + (size_t)idx * 8) = v;
}

// ---------------------------------------------------------------------------
// Kernel 3: bf16 GEMM, m97 structure.
// A = x_bf16 (M x K row-major), B = w_bf16 (N x K row-major), C = A*B^T + bias
// 128x128 tile, BK=64, 256 threads (4 waves, 2x2 of 64x64 per wave),
// 16x16x32 bf16 MFMA, both tiles staged with global_load_lds width=16.
// ---------------------------------------------------------------------------
__global__ __launch_bounds__(256) void gemm_bf16(const uint16_t* __restrict__ A,
                                                 const uint16_t* __restrict__ B,
                                                 const float* __restrict__ bias,
                                                 float* __restrict__ C) {
  __shared__ __align__(16) uint16_t As[BM * BK];
  __shared__ __align__(16) uint16_t Bs[BN * BK];

  const int tid  = threadIdx.x;
  const int wave = tid >> 6;
  const int lane = tid & 63;
  const int n0 = blockIdx.x * BN;
  const int m0 = blockIdx.y * BM;
  const int wm = wave >> 1;     // 0..1
  const int wn = wave & 1;      // 0..1

  const int lrow = lane >> 3;   // 0..7 : row within 8-row chunk
  const int lcol = lane & 7;    // 0..7 : 16B chunk within 128B row

  f32x4 acc[4][4];
#pragma unroll
  for (int i = 0; i < 4; i++)
#pragma unroll
    for (int j = 0; j < 4; j++)
      acc[i][j] = (f32x4){0.f, 0.f, 0.f, 0.f};

  const int col  = lane & 15;
  const int quad = lane >> 4;

  for (int kt = 0; kt < K_IN / BK; kt++) {
    const int k0 = kt * BK;
    // ---- stage A and B tiles: each wave writes 4 chunks of 8 rows x 128B ----
#pragma unroll
    for (int c = 0; c < 4; c++) {
      const int br = (c * 4 + wave) * 8;  // base row of this chunk (0..120)
      const uint16_t* ga = A + (size_t)(m0 + br + lrow) * K_IN + (k0 + lcol * 8);
      __builtin_amdgcn_global_load_lds(
          (const __attribute__((address_space(1))) uint32_t*)ga,
          (__attribute__((address_space(3))) uint32_t*)(As + br * BK), 16, 0, 0);
      const uint16_t* gb = B + (size_t)(n0 + br + lrow) * K_IN + (k0 + lcol * 8);
      __builtin_amdgcn_global_load_lds(
          (const __attribute__((address_space(1))) uint32_t*)gb,
          (__attribute__((address_space(3))) uint32_t*)(Bs + br * BK), 16, 0, 0);
    }
    __syncthreads();   // drains vmcnt (global_load_lds) + barrier

    // ---- compute: 2 k-steps of 32, 16 MFMAs each ----
#pragma unroll
    for (int ki = 0; ki < 2; ki++) {
      bf16x8 af[4], bfr[4];
      const int kf = ki * 32 + quad * 8;
#pragma unroll
      for (int i = 0; i < 4; i++) {
        const int m = wm * 64 + i * 16 + col;
        af[i] = *(const bf16x8*)(As + m * BK + kf);
        const int n = wn * 64 + i * 16 + col;
        bfr[i] = *(const bf16x8*)(Bs + n * BK + kf);
      }
#pragma unroll
      for (int i = 0; i < 4; i++)
#pragma unroll
        for (int j = 0; j < 4; j++)
          acc[i][j] = __builtin_amdgcn_mfma_f32_16x16x32_bf16(af[i], bfr[j],
                                                              acc[i][j], 0, 0, 0);
    }
    __syncthreads();
  }

  // ---- epilogue: D row = quad*4 + r, col = lane&15 ----
#pragma unroll
  for (int i = 0; i < 4; i++) {
#pragma unroll
    for (int j = 0; j < 4; j++) {
      const int n = n0 + wn * 64 + j * 16 + col;
      const int m = m0 + wm * 64 + i * 16 + quad * 4;
      const float bv = bias[n];
      float* out = C + (size_t)m * N_OUT + n;
#pragma unroll
      for (int r = 0; r < 4; r++)
        out[(size_t)r * N_OUT] = acc[i][j][r] + bv;
    }
  }
}

// ---------------------------------------------------------------------------
// Fallback (ws too small): correct but slow fused kernel.
// One block per (token, 256 outputs); x row staged in LDS.
// ---------------------------------------------------------------------------
__global__ __launch_bounds__(256) void fallback_fused(const float* __restrict__ x,
                                                      const uint32_t* __restrict__ qw,
                                                      const uint32_t* __restrict__ qz,
                                                      const float* __restrict__ sc,
                                                      const float* __restrict__ bias,
                                                      float* __restrict__ out) {
  __shared__ float xs[K_IN];
  const int t = blockIdx.y;
  const int o = blockIdx.x * 256 + threadIdx.x;
  for (int i = threadIdx.x; i < K_IN; i += 256) xs[i] = x[(size_t)t * K_IN + i];
  __syncthreads();
  float acc = 0.f;
  const uint32_t* qwr = qw + (size_t)o * WPR;
  for (int g = 0; g < GROUPS; g++) {
    uint32_t zw = qz[o * (GROUPS / 8) + (g >> 3)];
    float zp = (float)((zw >> ((g & 7) * 4)) & 15u);
    float s = sc[o * GROUPS + g];
    float gacc = 0.f, gsum = 0.f;
    for (int w = 0; w < 8; w++) {
      uint32_t wv = qwr[g * 8 + w];
#pragma unroll
      for (int j = 0; j < 8; j++) {
        float xv = xs[g * 64 + w * 8 + j];
        gacc = fmaf((float)((wv >> (4 * j)) & 15u), xv, gacc);
        gsum += xv;
      }
    }
    acc += s * (gacc - zp * gsum);
  }
  out[(size_t)t * N_OUT + o] = acc + bias[o];
}

// ---------------------------------------------------------------------------
extern "C" void kernel_launch(void* const* d_in, const int* in_sizes, int n_in,
                              void* d_out, int out_size, void* d_ws, size_t ws_size,
                              hipStream_t stream) {
  (void)in_sizes; (void)n_in; (void)out_size;
  const float*    x    = (const float*)d_in[0];
  const uint32_t* qw   = (const uint32_t*)d_in[1];
  const uint32_t* qz   = (const uint32_t*)d_in[2];
  const float*    sc   = (const float*)d_in[3];
  const float*    bias = (const float*)d_in[4];
  float* out = (float*)d_out;

  const size_t xb_bytes = (size_t)M_TOK * K_IN * 2;    // 33.5 MB
  const size_t wb_bytes = (size_t)N_OUT * K_IN * 2;    // 90.2 MB

  if (ws_size >= xb_bytes + wb_bytes) {
    uint16_t* xb = (uint16_t*)d_ws;
    uint16_t* wb = (uint16_t*)((char*)d_ws + xb_bytes);
    convert_x<<<(M_TOK * K_IN) / (256 * 8), 256, 0, stream>>>(x, xb);
    dequant_w<<<(N_OUT * WPR) / 256, 256, 0, stream>>>(qw, qz, sc, wb);
    gemm_bf16<<<dim3(N_OUT / BN, M_TOK / BM), 256, 0, stream>>>(xb, wb, bias, out);
  } else {
    fallback_fused<<<dim3(N_OUT / 256, M_TOK), 256, 0, stream>>>(x, qw, qz, sc, bias, out);
  }
}

// Round 2
// 696.917 us; speedup vs baseline: 1.1259x; 1.1259x over previous
//
#include <hip/hip_runtime.h>
#include <stdint.h>

#define M_TOK 4096
#define K_IN  4096
#define N_OUT 11008
#define GROUPS 64
#define WPR 512            // packed words per weight row = K_IN/8

#define BM 128
#define BN 128
#define BK 64
#define TILES_M (M_TOK / BM)   // 32
#define TILES_N (N_OUT / BN)   // 86
#define GN 8                   // N-tiles per supertile

typedef __bf16 bf16x8 __attribute__((ext_vector_type(8)));
typedef float  f32x4  __attribute__((ext_vector_type(4)));

__device__ __forceinline__ uint16_t f2bf(float f) {
  uint32_t u = __float_as_uint(f);
  u += 0x7FFFu + ((u >> 16) & 1u);
  return (uint16_t)(u >> 16);
}

// ---------------------------------------------------------------------------
// Fused preprocessing: blocks [0, XBLK) convert x fp32->bf16 (8 elem/thread),
// blocks [XBLK, XBLK+WBLK) dequantize int4 W -> bf16 (1 word/thread).
// Both memory-bound; fusing lets them occupy the machine together.
// ---------------------------------------------------------------------------
#define XBLK ((M_TOK * K_IN) / (256 * 8))        // 8192
#define WBLK ((N_OUT * WPR) / 256)               // 22016

__global__ __launch_bounds__(256) void prep(const float* __restrict__ x,
                                            const uint32_t* __restrict__ qw,
                                            const uint32_t* __restrict__ qz,
                                            const float* __restrict__ sc,
                                            uint16_t* __restrict__ xb,
                                            uint16_t* __restrict__ wb) {
  if (blockIdx.x < XBLK) {
    size_t i = ((size_t)blockIdx.x * 256 + threadIdx.x) * 8;
    const float4* p = (const float4*)(x + i);
    float4 a = p[0];
    float4 b = p[1];
    uint4 v;
    v.x = (uint32_t)f2bf(a.x) | ((uint32_t)f2bf(a.y) << 16);
    v.y = (uint32_t)f2bf(a.z) | ((uint32_t)f2bf(a.w) << 16);
    v.z = (uint32_t)f2bf(b.x) | ((uint32_t)f2bf(b.y) << 16);
    v.w = (uint32_t)f2bf(b.z) | ((uint32_t)f2bf(b.w) << 16);
    *(uint4*)(xb + i) = v;
  } else {
    int idx = (blockIdx.x - XBLK) * 256 + threadIdx.x;  // word index
    int o = idx >> 9;
    int p = idx & 511;
    int g = p >> 3;
    uint32_t zw = qz[o * (GROUPS / 8) + (g >> 3)];
    float zp = (float)((zw >> ((g & 7) * 4)) & 15u);
    float s = sc[o * GROUPS + g];
    float c = -s * zp;
    uint32_t w = qw[idx];
    uint4 v;
    uint32_t r[4];
#pragma unroll
    for (int j = 0; j < 4; j++) {
      float f0 = (float)((w >> (8 * j)) & 15u);
      float f1 = (float)((w >> (8 * j + 4)) & 15u);
      r[j] = (uint32_t)f2bf(fmaf(f0, s, c)) | ((uint32_t)f2bf(fmaf(f1, s, c)) << 16);
    }
    v.x = r[0]; v.y = r[1]; v.z = r[2]; v.w = r[3];
    *(uint4*)(wb + (size_t)idx * 8) = v;
  }
}

// ---------------------------------------------------------------------------
// bf16 GEMM: A (MxK rm) * B^T (NxK rm) + bias. 128x128x64 tile, 4 waves.
// XOR-swizzled LDS (kills the 16-way bank conflict on fragment reads),
// supertile block order (L3 locality), nontemporal C stores.
// ---------------------------------------------------------------------------
__global__ __launch_bounds__(256) void gemm_bf16(const uint16_t* __restrict__ A,
                                                 const uint16_t* __restrict__ B,
                                                 const float* __restrict__ bias,
                                                 float* __restrict__ C) {
  __shared__ __align__(16) uint16_t As[BM * BK];
  __shared__ __align__(16) uint16_t Bs[BN * BK];

  // --- supertile swizzle: groups of GN n-tiles x all m-tiles ---
  int bid = blockIdx.x;
  int nt, mt;
  const int full = (TILES_N / GN) * GN * TILES_M;   // 2560
  if (bid < full) {
    int group = bid >> 8;          // / (GN*TILES_M) = /256
    int rem = bid & 255;
    nt = group * GN + (rem & (GN - 1));
    mt = rem >> 3;
  } else {
    int rem = bid - full;          // tail: 6 n-tiles x 32 m-tiles
    nt = (TILES_N / GN) * GN + rem % (TILES_N % GN);
    mt = rem / (TILES_N % GN);
  }
  const int n0 = nt * BN;
  const int m0 = mt * BM;

  const int tid  = threadIdx.x;
  const int wave = tid >> 6;
  const int lane = tid & 63;
  const int wm = wave >> 1;
  const int wn = wave & 1;

  const int lrow = lane >> 3;           // 0..7
  const int lcol = lane & 7;            // 0..7
  const int scol = lcol ^ lrow;         // swizzled global k-chunk

  f32x4 acc[4][4];
#pragma unroll
  for (int i = 0; i < 4; i++)
#pragma unroll
    for (int j = 0; j < 4; j++)
      acc[i][j] = (f32x4){0.f, 0.f, 0.f, 0.f};

  const int col  = lane & 15;
  const int quad = lane >> 4;
  const int cs   = col & 7;             // swizzle key for fragment reads

  for (int kt = 0; kt < K_IN / BK; kt++) {
    const int k0 = kt * BK;
#pragma unroll
    for (int c = 0; c < 4; c++) {
      const int br = (c * 4 + wave) * 8;
      const uint16_t* ga = A + (size_t)(m0 + br + lrow) * K_IN + (k0 + scol * 8);
      __builtin_amdgcn_global_load_lds(
          (const __attribute__((address_space(1))) uint32_t*)ga,
          (__attribute__((address_space(3))) uint32_t*)(As + br * BK), 16, 0, 0);
      const uint16_t* gb = B + (size_t)(n0 + br + lrow) * K_IN + (k0 + scol * 8);
      __builtin_amdgcn_global_load_lds(
          (const __attribute__((address_space(1))) uint32_t*)gb,
          (__attribute__((address_space(3))) uint32_t*)(Bs + br * BK), 16, 0, 0);
    }
    __syncthreads();

#pragma unroll
    for (int ki = 0; ki < 2; ki++) {
      bf16x8 af[4], bfr[4];
      const int kc = ki * 4 + quad;     // k-chunk index 0..7
#pragma unroll
      for (int i = 0; i < 4; i++) {
        const int m = wm * 64 + i * 16 + col;
        af[i] = *(const bf16x8*)(As + m * BK + ((kc ^ cs) << 3));
        const int n = wn * 64 + i * 16 + col;
        bfr[i] = *(const bf16x8*)(Bs + n * BK + ((kc ^ cs) << 3));
      }
#pragma unroll
      for (int i = 0; i < 4; i++)
#pragma unroll
        for (int j = 0; j < 4; j++)
          acc[i][j] = __builtin_amdgcn_mfma_f32_16x16x32_bf16(af[i], bfr[j],
                                                              acc[i][j], 0, 0, 0);
    }
    __syncthreads();
  }

  // epilogue: D row = quad*4 + r, col = lane&15; nontemporal stores
#pragma unroll
  for (int i = 0; i < 4; i++) {
#pragma unroll
    for (int j = 0; j < 4; j++) {
      const int n = n0 + wn * 64 + j * 16 + col;
      const int m = m0 + wm * 64 + i * 16 + quad * 4;
      const float bv = bias[n];
      float* out = C + (size_t)m * N_OUT + n;
#pragma unroll
      for (int r = 0; r < 4; r++)
        __builtin_nontemporal_store(acc[i][j][r] + bv, out + (size_t)r * N_OUT);
    }
  }
}

// ---------------------------------------------------------------------------
// Fallback (ws too small): correct but slow fused kernel.
// ---------------------------------------------------------------------------
__global__ __launch_bounds__(256) void fallback_fused(const float* __restrict__ x,
                                                      const uint32_t* __restrict__ qw,
                                                      const uint32_t* __restrict__ qz,
                                                      const float* __restrict__ sc,
                                                      const float* __restrict__ bias,
                                                      float* __restrict__ out) {
  __shared__ float xs[K_IN];
  const int t = blockIdx.y;
  const int o = blockIdx.x * 256 + threadIdx.x;
  for (int i = threadIdx.x; i < K_IN; i += 256) xs[i] = x[(size_t)t * K_IN + i];
  __syncthreads();
  float acc = 0.f;
  const uint32_t* qwr = qw + (size_t)o * WPR;
  for (int g = 0; g < GROUPS; g++) {
    uint32_t zw = qz[o * (GROUPS / 8) + (g >> 3)];
    float zp = (float)((zw >> ((g & 7) * 4)) & 15u);
    float s = sc[o * GROUPS + g];
    float gacc = 0.f, gsum = 0.f;
    for (int w = 0; w < 8; w++) {
      uint32_t wv = qwr[g * 8 + w];
#pragma unroll
      for (int j = 0; j < 8; j++) {
        float xv = xs[g * 64 + w * 8 + j];
        gacc = fmaf((float)((wv >> (4 * j)) & 15u), xv, gacc);
        gsum += xv;
      }
    }
    acc += s * (gacc - zp * gsum);
  }
  out[(size_t)t * N_OUT + o] = acc + bias[o];
}

// ---------------------------------------------------------------------------
extern "C" void kernel_launch(void* const* d_in, const int* in_sizes, int n_in,
                              void* d_out, int out_size, void* d_ws, size_t ws_size,
                              hipStream_t stream) {
  (void)in_sizes; (void)n_in; (void)out_size;
  const float*    x    = (const float*)d_in[0];
  const uint32_t* qw   = (const uint32_t*)d_in[1];
  const uint32_t* qz   = (const uint32_t*)d_in[2];
  const float*    sc   = (const float*)d_in[3];
  const float*    bias = (const float*)d_in[4];
  float* out = (float*)d_out;

  const size_t xb_bytes = (size_t)M_TOK * K_IN * 2;
  const size_t wb_bytes = (size_t)N_OUT * K_IN * 2;

  if (ws_size >= xb_bytes + wb_bytes) {
    uint16_t* xb = (uint16_t*)d_ws;
    uint16_t* wb = (uint16_t*)((char*)d_ws + xb_bytes);
    prep<<<XBLK + WBLK, 256, 0, stream>>>(x, qw, qz, sc, xb, wb);
    gemm_bf16<<<TILES_N * TILES_M, 256, 0, stream>>>(xb, wb, bias, out);
  } else {
    fallback_fused<<<dim3(N_OUT / 256, M_TOK), 256, 0, stream>>>(x, qw, qz, sc, bias, out);
  }
}